// Round 9
// baseline (297.332 us; speedup 1.0000x reference)
//
#include <hip/hip_runtime.h>
#include <hip/hip_fp16.h>
#include <math.h>

#define N_NODES 50000
#define N_EDGES 800000
#define NB 782            // ceil(50000/64) buckets of 64 dst nodes
#define CH 1024           // edges per k_bucket block (782 blocks ~ 3/CU)
#define CAP 2048          // arena slots per bucket (Poisson(1024) -> 2x slack)
#define BUCKET_BLOCKS 782 // 800000/1024 = 781.25 -> 782
#define PREPW_BLOCKS 192  // 3 * 16384/256
#define W3_BLOCKS 8       // 2048/256 (W3 -> fp16 transpose)
#define PREP_GRID (BUCKET_BLOCKS + PREPW_BLOCKS + W3_BLOCKS)
#define FB 1563           // ceil(50000/32) fused-layer blocks (32 nodes each)

typedef _Float16 half8 __attribute__((ext_vector_type(8)));
typedef float floatx4 __attribute__((ext_vector_type(4)));
typedef unsigned uintx4 __attribute__((ext_vector_type(4)));

// ---- pass 1 (merged): bucket scatter | W->fp16 W^T | WT3 ------------------
// Round-9 changes: CH 4096->1024 (196 -> 782 bucket blocks; the old config
// left >75% of CUs idle during the whole kernel) and the 16-barrier block
// scan replaced by a wave-shfl scan (2 barriers). Numerics identical.
__global__ __launch_bounds__(256) void k_bucket_prep(
    const int* __restrict__ src, const int* __restrict__ dst,
    int* __restrict__ gcur, unsigned* __restrict__ arena,
    const float* __restrict__ W0, const float* __restrict__ W1,
    const float* __restrict__ W2, const float* __restrict__ W3,
    __half* __restrict__ WT, __half* __restrict__ WT3) {
    const int t = threadIdx.x;
    if (blockIdx.x >= BUCKET_BLOCKS) {
        int idx = blockIdx.x - BUCKET_BLOCKS;  // 0..199
        if (idx < PREPW_BLOCKS) {
            int which = idx >> 6;
            const float* W = (which == 0) ? W0 : (which == 1) ? W1 : W2;
            int i = (idx & 63) * 256 + t;  // i = k*128 + n
            int k = i >> 7, n = i & 127;
            int np = ((n & 7) << 4) + (n >> 3);  // perm^-1
            WT[which * 128 * 128 + np * 128 + k] = __float2half(W[i]);
        } else {
            int i = (idx - PREPW_BLOCKS) * 256 + t;  // 0..2047
            int n = i >> 7, k = i & 127;             // W3: [128][16]
            WT3[n * 128 + k] = __float2half(W3[k * 16 + n]);
        }
        return;
    }
    __shared__ int cntA[NB];
    __shared__ int lofs[NB];
    __shared__ int gbase[NB];
    __shared__ int wsum[4];
    __shared__ unsigned buf[CH];
    const int ebase = blockIdx.x * CH;
    const int chunkN = min(CH, N_EDGES - ebase);

    for (int i = t; i < NB; i += 256) cntA[i] = 0;
    __syncthreads();
    for (int i = t; i < chunkN; i += 256)
        atomicAdd(&cntA[dst[ebase + i] >> 6], 1);
    __syncthreads();
    int c[4];
    int s = 0;
#pragma unroll
    for (int q = 0; q < 4; ++q) {
        int idx = t * 4 + q;
        c[q] = (idx < NB) ? cntA[idx] : 0;
        s += c[q];
    }
    // exclusive scan of s across 256 threads: wave shfl + 4 wave sums
    const int lane = t & 63, wid = t >> 6;
    int p = s;
#pragma unroll
    for (int off = 1; off < 64; off <<= 1) {
        int u = __shfl_up(p, off, 64);
        if (lane >= off) p += u;
    }
    if (lane == 63) wsum[wid] = p;
    __syncthreads();
    int wbase = 0;
#pragma unroll
    for (int w = 0; w < 4; ++w) wbase += (w < wid) ? wsum[w] : 0;
    int run = wbase + p - s;  // exclusive prefix for this thread's 4 bins
#pragma unroll
    for (int q = 0; q < 4; ++q) {
        int idx = t * 4 + q;
        if (idx < NB) {
            lofs[idx] = run;
            run += c[q];
            gbase[idx] = (c[q] > 0) ? atomicAdd(&gcur[idx], c[q]) : 0;
            cntA[idx] = 0;  // reuse as placement cursor
        }
    }
    __syncthreads();
    for (int i = t; i < chunkN; i += 256) {
        int d = dst[ebase + i];
        int sv = src[ebase + i];
        int b = d >> 6;
        int pos = atomicAdd(&cntA[b], 1);
        buf[lofs[b] + pos] = ((unsigned)d << 16) | (unsigned)sv;
    }
    __syncthreads();
    for (int i = t; i < chunkN; i += 256) {
        unsigned v = buf[i];
        int b = (int)(v >> 16) >> 6;
        int q = i - lofs[b];
        int p2 = gbase[b] + q;
        if (p2 < CAP) arena[((size_t)b << 11) + p2] = v;
    }
}

// ---- pass 2: bucket finalize (dinv, packed, eidx) + x->fp16 cast ----------
__global__ __launch_bounds__(256) void k_fill(
    const unsigned* __restrict__ arena, const int* __restrict__ gcur,
    unsigned* __restrict__ packed, float* __restrict__ dinv,
    unsigned short* __restrict__ eidx, const float* __restrict__ x,
    __half* __restrict__ xh) {
    const int t = threadIdx.x;
    const int b = blockIdx.x;
    __shared__ int cnt64[64];
    __shared__ int cur64[64];
    if (t < 64) cnt64[t] = 0;
    __syncthreads();
    const int seglen = min(gcur[b], CAP);
    const unsigned* seg = arena + ((size_t)b << 11);
    for (int i = t; i < seglen; i += 256)
        atomicAdd(&cnt64[(seg[i] >> 16) & 63], 1);
    __syncthreads();
    if (t < 64) {  // one wave: prefix scan of 64 counts
        int v = cnt64[t];
        int p = v;
#pragma unroll
        for (int d = 1; d < 64; d <<= 1) {
            int u = __shfl_up(p, d, 64);
            if (t >= d) p += u;
        }
        int excl = p - v;
        int node = b * 64 + t;
        if (node < N_NODES) {
            packed[node] = ((unsigned)((b << 11) + excl) << 11) | (unsigned)v;
            dinv[node] = rsqrtf((float)v + 2.0f);  // improved: +2
        }
        cur64[t] = excl;
    }
    __syncthreads();
    const int base = b << 11;
    for (int i = t; i < seglen; i += 256) {
        unsigned v = seg[i];
        int d = (int)(v >> 16) & 63;
        int pos = atomicAdd(&cur64[d], 1);
        eidx[base + pos] = (unsigned short)(v & 0xFFFFu);
    }
    // fused cast: this bucket's 64 rows (64*128 floats = 2048 float4)
    const int rowbase = b * 64;
#pragma unroll
    for (int it = 0; it < 8; ++it) {
        int id = it * 256 + t;          // 0..2047
        int row = rowbase + (id >> 5);  // 32 float4 per row
        int c4 = id & 31;
        if (row < N_NODES) {
            float4 v = *(const float4*)&x[(size_t)row * 128 + c4 * 4];
            union { ushort4 u; __half h[4]; } p;
            p.h[0] = __float2half(v.x); p.h[1] = __float2half(v.y);
            p.h[2] = __float2half(v.z); p.h[3] = __float2half(v.w);
            *(ushort4*)&xh[(size_t)row * 128 + c4 * 4] = p.u;
        }
    }
}

// ---- scaled 256B-row accumulate: acc[0..15] += s * row -------------------
__device__ __forceinline__ void accs(uint4 ua, uint4 ub, float s, float* acc) {
    union { uint4 u; __half2 h2[4]; } va, vb;
    va.u = ua; vb.u = ub;
#pragma unroll
    for (int q = 0; q < 4; ++q) {
        float2 wa = __half22float2(va.h2[q]);
        float2 wb = __half22float2(vb.h2[q]);
        acc[2 * q]     += s * wa.x;
        acc[2 * q + 1] += s * wa.y;
        acc[8 + 2 * q]     += s * wb.x;
        acc[8 + 2 * q + 1] += s * wb.y;
    }
}

// ---- shared gather stage: acc = 2*p_r (+dinv scaling) + sum p_src ---------
// Round-4/6 geometry (best measured): 32 nodes/block, 8 lanes/node, 8-edge
// batches = 16 outstanding uint4/lane; VGPR ~56 -> under the 64 cliff.
template <bool SC>
__device__ __forceinline__ void gather_stage(
    int r, bool valid, int l8, const __half* __restrict__ pin,
    const float* __restrict__ dinv, const unsigned* __restrict__ packed,
    const unsigned short* __restrict__ eidx, float* acc) {
#pragma unroll
    for (int j = 0; j < 16; ++j) acc[j] = 0.f;
    int i = 0, end = 0;
    if (valid) {
        const uint4* rp = (const uint4*)&pin[(size_t)r * 128];
        uint4 sa = rp[l8], sb = rp[8 + l8];
        float s2 = SC ? 2.f * dinv[r] : 2.f;
        accs(sa, sb, s2, acc);
        unsigned pk = packed[r];
        i = (int)(pk >> 11);
        end = i + (int)(pk & 2047u);
    }
    for (; i + 8 <= end; i += 8) {
        int my = (int)eidx[i + l8];
        uint4 va[8], vb[8];
        float ds8[8];
#pragma unroll
        for (int j = 0; j < 8; ++j) {
            int s0 = __shfl(my, j, 8);
            const uint4* q = (const uint4*)&pin[(size_t)s0 * 128];
            va[j] = q[l8];
            vb[j] = q[8 + l8];
            if (SC) ds8[j] = dinv[s0];
        }
#pragma unroll
        for (int j = 0; j < 8; ++j)
            accs(va[j], vb[j], SC ? ds8[j] : 1.f, acc);
    }
    if (i < end) {
        int n = end - i;
        int my = (l8 < n) ? (int)eidx[i + l8] : 0;
        for (int j = 0; j < n; ++j) {
            int s0 = __shfl(my, j, 8);
            const uint4* q = (const uint4*)&pin[(size_t)s0 * 128];
            accs(q[l8], q[8 + l8], SC ? dinv[s0] : 1.f, acc);
        }
    }
}

// ====== fused layer: t = 2*p_r + sum p_src  ->  p_next = relu(dv*(dv*tW+b))
template <bool SC>
__global__ __launch_bounds__(256, 2) void k_fused(
    const __half* __restrict__ pin, const __half* __restrict__ WTl,
    const float* __restrict__ dinv, const unsigned* __restrict__ packed,
    const unsigned short* __restrict__ eidx, const float* __restrict__ bias,
    __half* __restrict__ pout) {
    __shared__ __half tl[32 * 136];  // +8 pad: conflict-free b128 r/w
    const int t = threadIdx.x;
    const int node8 = t >> 3;
    const int l8 = t & 7;
    const int r = blockIdx.x * 32 + node8;

    float acc[16];
    gather_stage<SC>(r, r < N_NODES, l8, pin, dinv, packed, eidx, acc);

    {
        union { uintx4 u; __half h[8]; } pa, pb;
#pragma unroll
        for (int j = 0; j < 8; ++j) {
            pa.h[j] = __float2half(acc[j]);
            pb.h[j] = __float2half(acc[8 + j]);
        }
        *(uintx4*)&tl[node8 * 136 + 8 * l8] = pa.u;
        *(uintx4*)&tl[node8 * 136 + 64 + 8 * l8] = pb.u;
    }
    __syncthreads();

    // MFMA: 4 waves = 2 row-tiles x 2 col-tiles; 16 mfma each
    const int wave = t >> 6;
    const int lane = t & 63;
    const int m = lane & 15;
    const int quad = lane >> 4;
    const int rtile = wave >> 1;
    const int ctile = wave & 1;
    floatx4 a4[4] = {};
#pragma unroll
    for (int kb = 0; kb < 4; ++kb) {
        half8 af = *(const half8*)&tl[(rtile * 16 + m) * 136 + quad * 8 + kb * 32];
#pragma unroll
        for (int j = 0; j < 4; ++j) {
            half8 bf = *(const half8*)&WTl[(size_t)(((ctile * 4 + j) * 16 + m)) * 128 +
                                           kb * 32 + quad * 8];
            a4[j] = __builtin_amdgcn_mfma_f32_16x16x32_f16(af, bf, a4[j], 0, 0, 0);
        }
    }
    // feature f = 8m + ctile*4 + j ; node = base + rtile*16 + quad*4 + rr
    const int f0 = 8 * m + ctile * 4;
    const float4 bi = *(const float4*)&bias[f0];
    const int nb0 = blockIdx.x * 32 + rtile * 16 + quad * 4;
#pragma unroll
    for (int rr = 0; rr < 4; ++rr) {
        int node = nb0 + rr;
        if (node < N_NODES) {
            float dv = dinv[node];
            union { ushort4 u; __half h[4]; } pk4;
            pk4.h[0] = __float2half(fmaxf(dv * (dv * a4[0][rr] + bi.x), 0.f));
            pk4.h[1] = __float2half(fmaxf(dv * (dv * a4[1][rr] + bi.y), 0.f));
            pk4.h[2] = __float2half(fmaxf(dv * (dv * a4[2][rr] + bi.z), 0.f));
            pk4.h[3] = __float2half(fmaxf(dv * (dv * a4[3][rr] + bi.w), 0.f));
            *(ushort4*)&pout[(size_t)node * 128 + f0] = pk4.u;
        }
    }
}

// ====== last fused layer: gather + GEMM(W2) + relu + GEMM(W3) -> H16 =======
__global__ __launch_bounds__(256, 2) void k_fused_last(
    const __half* __restrict__ pin, const __half* __restrict__ WTl,
    const __half* __restrict__ WT3, const float* __restrict__ dinv,
    const unsigned* __restrict__ packed, const unsigned short* __restrict__ eidx,
    const float* __restrict__ bias, float* __restrict__ H16) {
    __shared__ __half tl[32 * 136];
    const int t = threadIdx.x;
    const int node8 = t >> 3;
    const int l8 = t & 7;
    const int r = blockIdx.x * 32 + node8;

    float acc[16];
    gather_stage<false>(r, r < N_NODES, l8, pin, dinv, packed, eidx, acc);

    {
        union { uintx4 u; __half h[8]; } pa, pb;
#pragma unroll
        for (int j = 0; j < 8; ++j) {
            pa.h[j] = __float2half(acc[j]);
            pb.h[j] = __float2half(acc[8 + j]);
        }
        *(uintx4*)&tl[node8 * 136 + 8 * l8] = pa.u;
        *(uintx4*)&tl[node8 * 136 + 64 + 8 * l8] = pb.u;
    }
    __syncthreads();

    const int wave = t >> 6;
    const int lane = t & 63;
    const int m = lane & 15;
    const int quad = lane >> 4;
    const int rtile = wave >> 1;
    const int ctile = wave & 1;
    floatx4 a4[4] = {};
#pragma unroll
    for (int kb = 0; kb < 4; ++kb) {
        half8 af = *(const half8*)&tl[(rtile * 16 + m) * 136 + quad * 8 + kb * 32];
#pragma unroll
        for (int j = 0; j < 4; ++j) {
            half8 bf = *(const half8*)&WTl[(size_t)(((ctile * 4 + j) * 16 + m)) * 128 +
                                           kb * 32 + quad * 8];
            a4[j] = __builtin_amdgcn_mfma_f32_16x16x32_f16(af, bf, a4[j], 0, 0, 0);
        }
    }
    __syncthreads();  // everyone done reading tl; reuse it for the p3 tile

    // p3 = relu(dv*(dv*a4+b2)) -> LDS (fp16, same rounding as before)
    const int f0 = 8 * m + ctile * 4;
    const float4 bi = *(const float4*)&bias[f0];
    const int rowb = rtile * 16 + quad * 4;
#pragma unroll
    for (int rr = 0; rr < 4; ++rr) {
        int node = blockIdx.x * 32 + rowb + rr;
        float dv = (node < N_NODES) ? dinv[node] : 0.f;
        union { ushort4 u; __half h[4]; } pk4;
        pk4.h[0] = __float2half(fmaxf(dv * (dv * a4[0][rr] + bi.x), 0.f));
        pk4.h[1] = __float2half(fmaxf(dv * (dv * a4[1][rr] + bi.y), 0.f));
        pk4.h[2] = __float2half(fmaxf(dv * (dv * a4[2][rr] + bi.z), 0.f));
        pk4.h[3] = __float2half(fmaxf(dv * (dv * a4[3][rr] + bi.w), 0.f));
        *(ushort4*)&tl[(rowb + rr) * 136 + f0] = pk4.u;
    }
    __syncthreads();

    // second MFMA: M=32 x N=16 x K=128 on waves 0-1 (wave = row-tile)
    if (wave < 2) {
        floatx4 c2 = {};
#pragma unroll
        for (int kb = 0; kb < 4; ++kb) {
            half8 af2 = *(const half8*)&tl[(wave * 16 + m) * 136 + quad * 8 + kb * 32];
            half8 bf2 = *(const half8*)&WT3[(size_t)m * 128 + kb * 32 + quad * 8];
            c2 = __builtin_amdgcn_mfma_f32_16x16x32_f16(af2, bf2, c2, 0, 0, 0);
        }
        // C layout: col = m (output class), row = quad*4 + rr
#pragma unroll
        for (int rr = 0; rr < 4; ++rr) {
            int node = blockIdx.x * 32 + wave * 16 + quad * 4 + rr;
            if (node < N_NODES) H16[(size_t)node * 16 + m] = c2[rr];
        }
    }
}

// ====== fp32 gather for the last (F=16) layer ======
__global__ __launch_bounds__(256) void k_gather4(const unsigned* __restrict__ packed,
                                                 const unsigned short* __restrict__ eidx,
                                                 const float* __restrict__ hs,
                                                 const float* __restrict__ dinv,
                                                 const float* __restrict__ bias,
                                                 float* __restrict__ out) {
    int tid = blockIdx.x * 256 + threadIdx.x;
    int r = tid >> 2;
    if (r >= N_NODES) return;
    int l = tid & 3;
    int f = l * 4;
    const float dv = dinv[r];
    const float4 bi = *(const float4*)&bias[f];
    float4 h = *(const float4*)&hs[(size_t)r * 16 + f];
    float ax = 2.f * h.x, ay = 2.f * h.y, az = 2.f * h.z, aw = 2.f * h.w;
    unsigned pk = packed[r];
    int i = (int)(pk >> 11);
    int end = i + (int)(pk & 2047u);
    for (; i + 4 <= end; i += 4) {
        int my = (int)eidx[i + l];
#pragma unroll
        for (int j = 0; j < 4; ++j) {
            int s = __shfl(my, j, 4);
            float4 v = *(const float4*)&hs[(size_t)s * 16 + f];
            ax += v.x; ay += v.y; az += v.z; aw += v.w;
        }
    }
    if (i < end) {
        int n = end - i;
        int my = (l < n) ? (int)eidx[i + l] : 0;
        for (int j = 0; j < n; ++j) {
            int s = __shfl(my, j, 4);
            float4 v = *(const float4*)&hs[(size_t)s * 16 + f];
            ax += v.x; ay += v.y; az += v.z; aw += v.w;
        }
    }
    float v0 = tanhf(dv * ax + bi.x);
    float v1 = tanhf(dv * ay + bi.y);
    float v2 = tanhf(dv * az + bi.z);
    float v3 = tanhf(dv * aw + bi.w);
    floatx4 o = {v0, v1, v2, v3};
    __builtin_nontemporal_store(o, (floatx4*)&out[(size_t)r * 16 + f]);
}

extern "C" void kernel_launch(void* const* d_in, const int* in_sizes, int n_in,
                              void* d_out, int out_size, void* d_ws, size_t ws_size,
                              hipStream_t stream) {
    const float* x  = (const float*)d_in[0];
    const int* ei   = (const int*)d_in[1];
    const float* W0 = (const float*)d_in[2];
    const float* b0 = (const float*)d_in[3];
    const float* W1 = (const float*)d_in[4];
    const float* b1 = (const float*)d_in[5];
    const float* W2 = (const float*)d_in[6];
    const float* b2 = (const float*)d_in[7];
    const float* W3 = (const float*)d_in[8];
    const float* b3 = (const float*)d_in[9];
    const int* src = ei;
    const int* dst = ei + N_EDGES;

    // ws layout (16B-aligned):
    __half* A      = (__half*)d_ws;                        // 50000*128 f16 (ping)
    __half* P      = A + (size_t)N_NODES * 128;            // 50000*128 f16 (pong)
    __half* WT     = P + (size_t)N_NODES * 128;            // 3*128*128 f16
    __half* WT3    = WT + 3 * 128 * 128;                   // 16*128 f16
    float*  H16    = (float*)(WT3 + 16 * 128);             // 50000*16 f32
    float*  dinv   = H16 + (size_t)N_NODES * 16;           // 50000
    unsigned* packed = (unsigned*)(dinv + N_NODES);        // 50000
    int*    gcur   = (int*)(packed + N_NODES);             // 1024 (NB padded)
    unsigned short* eidx = (unsigned short*)(gcur + 1024); // NB*CAP u16
    unsigned* arena = (unsigned*)(eidx + NB * CAP);        // NB*CAP

    // ---- CSR build + prep (every call; ws is re-poisoned) ----
    (void)hipMemsetAsync(gcur, 0, 1024 * sizeof(int), stream);
    k_bucket_prep<<<PREP_GRID, 256, 0, stream>>>(src, dst, gcur, arena,
                                                 W0, W1, W2, W3, WT, WT3);
    k_fill<<<NB, 256, 0, stream>>>(arena, gcur, packed, dinv, eidx, x, A);

    // ---- fused layers: gather(p) -> MFMA -> p_next ----
    k_fused<true><<<FB, 256, 0, stream>>>(A, WT, dinv, packed, eidx, b0, P);
    k_fused<false><<<FB, 256, 0, stream>>>(P, WT + 128 * 128, dinv, packed,
                                           eidx, b1, A);
    // ---- layer 2 + layer-3 dense transform fused ----
    k_fused_last<<<FB, 256, 0, stream>>>(A, WT + 2 * 128 * 128, WT3, dinv,
                                         packed, eidx, b2, H16);
    // ---- layer 3 aggregate (F=16, tanh) ----
    k_gather4<<<(N_NODES * 4 + 255) / 256, 256, 0, stream>>>(
        packed, eidx, H16, dinv, b3, (float*)d_out);
}

// Round 10
// 237.585 us; speedup vs baseline: 1.2515x; 1.2515x over previous
//
#include <hip/hip_runtime.h>
#include <hip/hip_fp16.h>
#include <math.h>

#define N_NODES 50000
#define N_EDGES 800000
#define NB 782            // ceil(50000/64) buckets of 64 dst nodes
#define CH 4096           // edges per bucket block (4/thread at 1024 threads)
#define CAP 2048          // arena slots per bucket (Poisson(1024) -> 2x slack)
#define BUCKET_BLOCKS 196 // ceil(800000/4096)
#define PREPW_BLOCKS 48   // 3 * 16384/1024
#define W3_BLOCKS 2       // 2048/1024 (W3 -> fp16 transpose)
#define PREP_GRID (BUCKET_BLOCKS + PREPW_BLOCKS + W3_BLOCKS)
#define FB 1563           // ceil(50000/32) fused-layer blocks (32 nodes each)

typedef _Float16 half8 __attribute__((ext_vector_type(8)));
typedef float floatx4 __attribute__((ext_vector_type(4)));
typedef unsigned uintx4 __attribute__((ext_vector_type(4)));

// ---- pass 1 (merged): bucket scatter | W->fp16 W^T | WT3 ------------------
// Round-10: 196 bucket blocks x 1024 threads (was 256). Round-9 showed
// per-block fixed cost (bin zero/scan, gcur atomics) x block-count is the
// cost driver -> raise lanes per block, not block count. Each serialized
// phase gets 4x lanes at the SAME total fixed cost; a CU hosting a block
// runs 16 waves not 4. Edges loaded once as int4 and reused across phases.
__global__ __launch_bounds__(1024) void k_bucket_prep(
    const int* __restrict__ src, const int* __restrict__ dst,
    int* __restrict__ gcur, unsigned* __restrict__ arena,
    const float* __restrict__ W0, const float* __restrict__ W1,
    const float* __restrict__ W2, const float* __restrict__ W3,
    __half* __restrict__ WT, __half* __restrict__ WT3) {
    const int t = threadIdx.x;
    if (blockIdx.x >= BUCKET_BLOCKS) {
        int idx = blockIdx.x - BUCKET_BLOCKS;  // 0..49
        if (idx < PREPW_BLOCKS) {
            int which = idx >> 4;
            const float* W = (which == 0) ? W0 : (which == 1) ? W1 : W2;
            int i = (idx & 15) * 1024 + t;  // i = k*128 + n, 16384/matrix
            int k = i >> 7, n = i & 127;
            int np = ((n & 7) << 4) + (n >> 3);  // perm^-1
            WT[which * 128 * 128 + np * 128 + k] = __float2half(W[i]);
        } else {
            int i = (idx - PREPW_BLOCKS) * 1024 + t;  // 0..2047
            int n = i >> 7, k = i & 127;              // W3: [128][16]
            WT3[n * 128 + k] = __float2half(W3[k * 16 + n]);
        }
        return;
    }
    __shared__ int cntA[NB];
    __shared__ int lofs[NB];
    __shared__ int gbase[NB];
    __shared__ int wsum[16];
    __shared__ unsigned buf[CH];
    const int ebase = blockIdx.x * CH;
    const int chunkN = min(CH, N_EDGES - ebase);  // multiple of 4
    const bool act = (t * 4 < chunkN);

    int4 d4 = {0, 0, 0, 0}, s4 = {0, 0, 0, 0};
    if (act) {
        d4 = *(const int4*)&dst[ebase + t * 4];
        s4 = *(const int4*)&src[ebase + t * 4];
    }
    if (t < NB) cntA[t] = 0;
    __syncthreads();
    if (act) {
        atomicAdd(&cntA[d4.x >> 6], 1);
        atomicAdd(&cntA[d4.y >> 6], 1);
        atomicAdd(&cntA[d4.z >> 6], 1);
        atomicAdd(&cntA[d4.w >> 6], 1);
    }
    __syncthreads();
    // exclusive scan over 782 bins, 1 bin/thread: wave shfl + 16 wave sums
    const int lane = t & 63, wid = t >> 6;
    int c = (t < NB) ? cntA[t] : 0;
    int p = c;
#pragma unroll
    for (int off = 1; off < 64; off <<= 1) {
        int u = __shfl_up(p, off, 64);
        if (lane >= off) p += u;
    }
    if (lane == 63) wsum[wid] = p;
    __syncthreads();
    int wbase = 0;
#pragma unroll
    for (int w = 0; w < 16; ++w) wbase += (w < wid) ? wsum[w] : 0;
    if (t < NB) {
        int run = wbase + p - c;
        lofs[t] = run;
        gbase[t] = (c > 0) ? atomicAdd(&gcur[t], c) : 0;
        cntA[t] = 0;  // reuse as placement cursor
    }
    __syncthreads();
    if (act) {
#pragma unroll
        for (int e = 0; e < 4; ++e) {
            int d = (e == 0) ? d4.x : (e == 1) ? d4.y : (e == 2) ? d4.z : d4.w;
            int sv = (e == 0) ? s4.x : (e == 1) ? s4.y : (e == 2) ? s4.z : s4.w;
            int b = d >> 6;
            int pos = atomicAdd(&cntA[b], 1);
            buf[lofs[b] + pos] = ((unsigned)d << 16) | (unsigned)sv;
        }
    }
    __syncthreads();
#pragma unroll
    for (int k = 0; k < 4; ++k) {
        int i = k * 1024 + t;
        if (i < chunkN) {
            unsigned v = buf[i];
            int b = (int)(v >> 16) >> 6;
            int q = i - lofs[b];
            int p2 = gbase[b] + q;
            if (p2 < CAP) arena[((size_t)b << 11) + p2] = v;
        }
    }
}

// ---- pass 2: bucket finalize (dinv, packed, eidx) + x->fp16 cast ----------
__global__ __launch_bounds__(256) void k_fill(
    const unsigned* __restrict__ arena, const int* __restrict__ gcur,
    unsigned* __restrict__ packed, float* __restrict__ dinv,
    unsigned short* __restrict__ eidx, const float* __restrict__ x,
    __half* __restrict__ xh) {
    const int t = threadIdx.x;
    const int b = blockIdx.x;
    __shared__ int cnt64[64];
    __shared__ int cur64[64];
    if (t < 64) cnt64[t] = 0;
    __syncthreads();
    const int seglen = min(gcur[b], CAP);
    const unsigned* seg = arena + ((size_t)b << 11);
    for (int i = t; i < seglen; i += 256)
        atomicAdd(&cnt64[(seg[i] >> 16) & 63], 1);
    __syncthreads();
    if (t < 64) {  // one wave: prefix scan of 64 counts
        int v = cnt64[t];
        int p = v;
#pragma unroll
        for (int d = 1; d < 64; d <<= 1) {
            int u = __shfl_up(p, d, 64);
            if (t >= d) p += u;
        }
        int excl = p - v;
        int node = b * 64 + t;
        if (node < N_NODES) {
            packed[node] = ((unsigned)((b << 11) + excl) << 11) | (unsigned)v;
            dinv[node] = rsqrtf((float)v + 2.0f);  // improved: +2
        }
        cur64[t] = excl;
    }
    __syncthreads();
    const int base = b << 11;
    for (int i = t; i < seglen; i += 256) {
        unsigned v = seg[i];
        int d = (int)(v >> 16) & 63;
        int pos = atomicAdd(&cur64[d], 1);
        eidx[base + pos] = (unsigned short)(v & 0xFFFFu);
    }
    // fused cast: this bucket's 64 rows (64*128 floats = 2048 float4)
    const int rowbase = b * 64;
#pragma unroll
    for (int it = 0; it < 8; ++it) {
        int id = it * 256 + t;          // 0..2047
        int row = rowbase + (id >> 5);  // 32 float4 per row
        int c4 = id & 31;
        if (row < N_NODES) {
            float4 v = *(const float4*)&x[(size_t)row * 128 + c4 * 4];
            union { ushort4 u; __half h[4]; } p;
            p.h[0] = __float2half(v.x); p.h[1] = __float2half(v.y);
            p.h[2] = __float2half(v.z); p.h[3] = __float2half(v.w);
            *(ushort4*)&xh[(size_t)row * 128 + c4 * 4] = p.u;
        }
    }
}

// ---- scaled 256B-row accumulate: acc[0..15] += s * row -------------------
__device__ __forceinline__ void accs(uint4 ua, uint4 ub, float s, float* acc) {
    union { uint4 u; __half2 h2[4]; } va, vb;
    va.u = ua; vb.u = ub;
#pragma unroll
    for (int q = 0; q < 4; ++q) {
        float2 wa = __half22float2(va.h2[q]);
        float2 wb = __half22float2(vb.h2[q]);
        acc[2 * q]     += s * wa.x;
        acc[2 * q + 1] += s * wa.y;
        acc[8 + 2 * q]     += s * wb.x;
        acc[8 + 2 * q + 1] += s * wb.y;
    }
}

// ---- shared gather stage: acc = 2*p_r (+dinv scaling) + sum p_src ---------
// Round-4/6 geometry (best measured): 32 nodes/block, 8 lanes/node, 8-edge
// batches = 16 outstanding uint4/lane; VGPR ~56 -> under the 64 cliff.
template <bool SC>
__device__ __forceinline__ void gather_stage(
    int r, bool valid, int l8, const __half* __restrict__ pin,
    const float* __restrict__ dinv, const unsigned* __restrict__ packed,
    const unsigned short* __restrict__ eidx, float* acc) {
#pragma unroll
    for (int j = 0; j < 16; ++j) acc[j] = 0.f;
    int i = 0, end = 0;
    if (valid) {
        const uint4* rp = (const uint4*)&pin[(size_t)r * 128];
        uint4 sa = rp[l8], sb = rp[8 + l8];
        float s2 = SC ? 2.f * dinv[r] : 2.f;
        accs(sa, sb, s2, acc);
        unsigned pk = packed[r];
        i = (int)(pk >> 11);
        end = i + (int)(pk & 2047u);
    }
    for (; i + 8 <= end; i += 8) {
        int my = (int)eidx[i + l8];
        uint4 va[8], vb[8];
        float ds8[8];
#pragma unroll
        for (int j = 0; j < 8; ++j) {
            int s0 = __shfl(my, j, 8);
            const uint4* q = (const uint4*)&pin[(size_t)s0 * 128];
            va[j] = q[l8];
            vb[j] = q[8 + l8];
            if (SC) ds8[j] = dinv[s0];
        }
#pragma unroll
        for (int j = 0; j < 8; ++j)
            accs(va[j], vb[j], SC ? ds8[j] : 1.f, acc);
    }
    if (i < end) {
        int n = end - i;
        int my = (l8 < n) ? (int)eidx[i + l8] : 0;
        for (int j = 0; j < n; ++j) {
            int s0 = __shfl(my, j, 8);
            const uint4* q = (const uint4*)&pin[(size_t)s0 * 128];
            accs(q[l8], q[8 + l8], SC ? dinv[s0] : 1.f, acc);
        }
    }
}

// ====== fused layer: t = 2*p_r + sum p_src  ->  p_next = relu(dv*(dv*tW+b))
template <bool SC>
__global__ __launch_bounds__(256, 2) void k_fused(
    const __half* __restrict__ pin, const __half* __restrict__ WTl,
    const float* __restrict__ dinv, const unsigned* __restrict__ packed,
    const unsigned short* __restrict__ eidx, const float* __restrict__ bias,
    __half* __restrict__ pout) {
    __shared__ __half tl[32 * 136];  // +8 pad: conflict-free b128 r/w
    const int t = threadIdx.x;
    const int node8 = t >> 3;
    const int l8 = t & 7;
    const int r = blockIdx.x * 32 + node8;

    float acc[16];
    gather_stage<SC>(r, r < N_NODES, l8, pin, dinv, packed, eidx, acc);

    {
        union { uintx4 u; __half h[8]; } pa, pb;
#pragma unroll
        for (int j = 0; j < 8; ++j) {
            pa.h[j] = __float2half(acc[j]);
            pb.h[j] = __float2half(acc[8 + j]);
        }
        *(uintx4*)&tl[node8 * 136 + 8 * l8] = pa.u;
        *(uintx4*)&tl[node8 * 136 + 64 + 8 * l8] = pb.u;
    }
    __syncthreads();

    // MFMA: 4 waves = 2 row-tiles x 2 col-tiles; 16 mfma each
    const int wave = t >> 6;
    const int lane = t & 63;
    const int m = lane & 15;
    const int quad = lane >> 4;
    const int rtile = wave >> 1;
    const int ctile = wave & 1;
    floatx4 a4[4] = {};
#pragma unroll
    for (int kb = 0; kb < 4; ++kb) {
        half8 af = *(const half8*)&tl[(rtile * 16 + m) * 136 + quad * 8 + kb * 32];
#pragma unroll
        for (int j = 0; j < 4; ++j) {
            half8 bf = *(const half8*)&WTl[(size_t)(((ctile * 4 + j) * 16 + m)) * 128 +
                                           kb * 32 + quad * 8];
            a4[j] = __builtin_amdgcn_mfma_f32_16x16x32_f16(af, bf, a4[j], 0, 0, 0);
        }
    }
    // feature f = 8m + ctile*4 + j ; node = base + rtile*16 + quad*4 + rr
    const int f0 = 8 * m + ctile * 4;
    const float4 bi = *(const float4*)&bias[f0];
    const int nb0 = blockIdx.x * 32 + rtile * 16 + quad * 4;
#pragma unroll
    for (int rr = 0; rr < 4; ++rr) {
        int node = nb0 + rr;
        if (node < N_NODES) {
            float dv = dinv[node];
            union { ushort4 u; __half h[4]; } pk4;
            pk4.h[0] = __float2half(fmaxf(dv * (dv * a4[0][rr] + bi.x), 0.f));
            pk4.h[1] = __float2half(fmaxf(dv * (dv * a4[1][rr] + bi.y), 0.f));
            pk4.h[2] = __float2half(fmaxf(dv * (dv * a4[2][rr] + bi.z), 0.f));
            pk4.h[3] = __float2half(fmaxf(dv * (dv * a4[3][rr] + bi.w), 0.f));
            *(ushort4*)&pout[(size_t)node * 128 + f0] = pk4.u;
        }
    }
}

// ====== last fused layer: gather + GEMM(W2) + relu + GEMM(W3) -> H16 =======
__global__ __launch_bounds__(256, 2) void k_fused_last(
    const __half* __restrict__ pin, const __half* __restrict__ WTl,
    const __half* __restrict__ WT3, const float* __restrict__ dinv,
    const unsigned* __restrict__ packed, const unsigned short* __restrict__ eidx,
    const float* __restrict__ bias, float* __restrict__ H16) {
    __shared__ __half tl[32 * 136];
    const int t = threadIdx.x;
    const int node8 = t >> 3;
    const int l8 = t & 7;
    const int r = blockIdx.x * 32 + node8;

    float acc[16];
    gather_stage<false>(r, r < N_NODES, l8, pin, dinv, packed, eidx, acc);

    {
        union { uintx4 u; __half h[8]; } pa, pb;
#pragma unroll
        for (int j = 0; j < 8; ++j) {
            pa.h[j] = __float2half(acc[j]);
            pb.h[j] = __float2half(acc[8 + j]);
        }
        *(uintx4*)&tl[node8 * 136 + 8 * l8] = pa.u;
        *(uintx4*)&tl[node8 * 136 + 64 + 8 * l8] = pb.u;
    }
    __syncthreads();

    const int wave = t >> 6;
    const int lane = t & 63;
    const int m = lane & 15;
    const int quad = lane >> 4;
    const int rtile = wave >> 1;
    const int ctile = wave & 1;
    floatx4 a4[4] = {};
#pragma unroll
    for (int kb = 0; kb < 4; ++kb) {
        half8 af = *(const half8*)&tl[(rtile * 16 + m) * 136 + quad * 8 + kb * 32];
#pragma unroll
        for (int j = 0; j < 4; ++j) {
            half8 bf = *(const half8*)&WTl[(size_t)(((ctile * 4 + j) * 16 + m)) * 128 +
                                           kb * 32 + quad * 8];
            a4[j] = __builtin_amdgcn_mfma_f32_16x16x32_f16(af, bf, a4[j], 0, 0, 0);
        }
    }
    __syncthreads();  // everyone done reading tl; reuse it for the p3 tile

    // p3 = relu(dv*(dv*a4+b2)) -> LDS (fp16, same rounding as before)
    const int f0 = 8 * m + ctile * 4;
    const float4 bi = *(const float4*)&bias[f0];
    const int rowb = rtile * 16 + quad * 4;
#pragma unroll
    for (int rr = 0; rr < 4; ++rr) {
        int node = blockIdx.x * 32 + rowb + rr;
        float dv = (node < N_NODES) ? dinv[node] : 0.f;
        union { ushort4 u; __half h[4]; } pk4;
        pk4.h[0] = __float2half(fmaxf(dv * (dv * a4[0][rr] + bi.x), 0.f));
        pk4.h[1] = __float2half(fmaxf(dv * (dv * a4[1][rr] + bi.y), 0.f));
        pk4.h[2] = __float2half(fmaxf(dv * (dv * a4[2][rr] + bi.z), 0.f));
        pk4.h[3] = __float2half(fmaxf(dv * (dv * a4[3][rr] + bi.w), 0.f));
        *(ushort4*)&tl[(rowb + rr) * 136 + f0] = pk4.u;
    }
    __syncthreads();

    // second MFMA: M=32 x N=16 x K=128 on waves 0-1 (wave = row-tile)
    if (wave < 2) {
        floatx4 c2 = {};
#pragma unroll
        for (int kb = 0; kb < 4; ++kb) {
            half8 af2 = *(const half8*)&tl[(wave * 16 + m) * 136 + quad * 8 + kb * 32];
            half8 bf2 = *(const half8*)&WT3[(size_t)m * 128 + kb * 32 + quad * 8];
            c2 = __builtin_amdgcn_mfma_f32_16x16x32_f16(af2, bf2, c2, 0, 0, 0);
        }
        // C layout: col = m (output class), row = quad*4 + rr
#pragma unroll
        for (int rr = 0; rr < 4; ++rr) {
            int node = blockIdx.x * 32 + wave * 16 + quad * 4 + rr;
            if (node < N_NODES) H16[(size_t)node * 16 + m] = c2[rr];
        }
    }
}

// ====== fp32 gather for the last (F=16) layer ======
__global__ __launch_bounds__(256) void k_gather4(const unsigned* __restrict__ packed,
                                                 const unsigned short* __restrict__ eidx,
                                                 const float* __restrict__ hs,
                                                 const float* __restrict__ dinv,
                                                 const float* __restrict__ bias,
                                                 float* __restrict__ out) {
    int tid = blockIdx.x * 256 + threadIdx.x;
    int r = tid >> 2;
    if (r >= N_NODES) return;
    int l = tid & 3;
    int f = l * 4;
    const float dv = dinv[r];
    const float4 bi = *(const float4*)&bias[f];
    float4 h = *(const float4*)&hs[(size_t)r * 16 + f];
    float ax = 2.f * h.x, ay = 2.f * h.y, az = 2.f * h.z, aw = 2.f * h.w;
    unsigned pk = packed[r];
    int i = (int)(pk >> 11);
    int end = i + (int)(pk & 2047u);
    for (; i + 4 <= end; i += 4) {
        int my = (int)eidx[i + l];
#pragma unroll
        for (int j = 0; j < 4; ++j) {
            int s = __shfl(my, j, 4);
            float4 v = *(const float4*)&hs[(size_t)s * 16 + f];
            ax += v.x; ay += v.y; az += v.z; aw += v.w;
        }
    }
    if (i < end) {
        int n = end - i;
        int my = (l < n) ? (int)eidx[i + l] : 0;
        for (int j = 0; j < n; ++j) {
            int s = __shfl(my, j, 4);
            float4 v = *(const float4*)&hs[(size_t)s * 16 + f];
            ax += v.x; ay += v.y; az += v.z; aw += v.w;
        }
    }
    float v0 = tanhf(dv * ax + bi.x);
    float v1 = tanhf(dv * ay + bi.y);
    float v2 = tanhf(dv * az + bi.z);
    float v3 = tanhf(dv * aw + bi.w);
    floatx4 o = {v0, v1, v2, v3};
    __builtin_nontemporal_store(o, (floatx4*)&out[(size_t)r * 16 + f]);
}

extern "C" void kernel_launch(void* const* d_in, const int* in_sizes, int n_in,
                              void* d_out, int out_size, void* d_ws, size_t ws_size,
                              hipStream_t stream) {
    const float* x  = (const float*)d_in[0];
    const int* ei   = (const int*)d_in[1];
    const float* W0 = (const float*)d_in[2];
    const float* b0 = (const float*)d_in[3];
    const float* W1 = (const float*)d_in[4];
    const float* b1 = (const float*)d_in[5];
    const float* W2 = (const float*)d_in[6];
    const float* b2 = (const float*)d_in[7];
    const float* W3 = (const float*)d_in[8];
    const float* b3 = (const float*)d_in[9];
    const int* src = ei;
    const int* dst = ei + N_EDGES;

    // ws layout (16B-aligned):
    __half* A      = (__half*)d_ws;                        // 50000*128 f16 (ping)
    __half* P      = A + (size_t)N_NODES * 128;            // 50000*128 f16 (pong)
    __half* WT     = P + (size_t)N_NODES * 128;            // 3*128*128 f16
    __half* WT3    = WT + 3 * 128 * 128;                   // 16*128 f16
    float*  H16    = (float*)(WT3 + 16 * 128);             // 50000*16 f32
    float*  dinv   = H16 + (size_t)N_NODES * 16;           // 50000
    unsigned* packed = (unsigned*)(dinv + N_NODES);        // 50000
    int*    gcur   = (int*)(packed + N_NODES);             // 1024 (NB padded)
    unsigned short* eidx = (unsigned short*)(gcur + 1024); // NB*CAP u16
    unsigned* arena = (unsigned*)(eidx + NB * CAP);        // NB*CAP

    // ---- CSR build + prep (every call; ws is re-poisoned) ----
    (void)hipMemsetAsync(gcur, 0, 1024 * sizeof(int), stream);
    k_bucket_prep<<<PREP_GRID, 1024, 0, stream>>>(src, dst, gcur, arena,
                                                  W0, W1, W2, W3, WT, WT3);
    k_fill<<<NB, 256, 0, stream>>>(arena, gcur, packed, dinv, eidx, x, A);

    // ---- fused layers: gather(p) -> MFMA -> p_next ----
    k_fused<true><<<FB, 256, 0, stream>>>(A, WT, dinv, packed, eidx, b0, P);
    k_fused<false><<<FB, 256, 0, stream>>>(P, WT + 128 * 128, dinv, packed,
                                           eidx, b1, A);
    // ---- layer 2 + layer-3 dense transform fused ----
    k_fused_last<<<FB, 256, 0, stream>>>(A, WT + 2 * 128 * 128, WT3, dinv,
                                         packed, eidx, b2, H16);
    // ---- layer 3 aggregate (F=16, tanh) ----
    k_gather4<<<(N_NODES * 4 + 255) / 256, 256, 0, stream>>>(
        packed, eidx, H16, dinv, b3, (float*)d_out);
}